// Round 1
// baseline (236.135 us; speedup 1.0000x reference)
//
#include <hip/hip_runtime.h>

// Swin-style attention: B=16, N=1024 (32x32), H=8, D=32, C=256.
// Pipeline: k_transpose_w (weights -> bf16, transposed) ; k_qkv (QKV proj GEMM,
// MFMA bf16) ; k_attn (flash attention + rel-pos bias) ; k_outproj (out GEMM).
// Workspace layout (bytes): [0,512K) WqT/WkT/WvT/WoT bf16 ; then Q,K (b,h,n,d),
// Vt (b,h,d,n), aout (b,n,256) bf16 -> total ~33 MB.

using f32x4  = __attribute__((ext_vector_type(4))) float;
using bf16x8 = __attribute__((ext_vector_type(8))) short;

__device__ __forceinline__ short f2bf(float f) {
  union { float f; unsigned u; } v; v.f = f;
  return (short)((v.u + 0x7FFFu + ((v.u >> 16) & 1u)) >> 16);  // RNE
}

__device__ __forceinline__ f32x4 mfma16(bf16x8 a, bf16x8 b, f32x4 c) {
  return __builtin_amdgcn_mfma_f32_16x16x32_bf16(a, b, c, 0, 0, 0);
}

// ---------------- kernel 0: weight transpose + bf16 cast ----------------
// W is (256,256) f32 row-major [k][n]; WT is bf16 [n][k] so MFMA B-fragments
// (8 consecutive k at fixed n) are contiguous 16B loads.
__global__ __launch_bounds__(256) void k_transpose_w(const float* __restrict__ W,
                                                     short* __restrict__ WT) {
  int n = blockIdx.x, k = threadIdx.x;
  WT[n * 256 + k] = f2bf(W[k * 256 + n]);
}

// ---------------- kernel 1: QKV projection ----------------
// Block = 64 rows of x (M = B*N = 16384). 4 waves, wave = 16 rows.
// Q,K out: [b][h][n][d] bf16 ; V out transposed: [b][h][d][n] bf16.
__global__ __launch_bounds__(256) void k_qkv(const float* __restrict__ x,
    const short* __restrict__ WqT, const short* __restrict__ WkT,
    const short* __restrict__ WvT,
    short* __restrict__ Q, short* __restrict__ K, short* __restrict__ Vt) {
  __shared__ short xt[64][264];  // +8 pad: row stride 528B keeps 16B align, spreads banks
  const int tid = threadIdx.x;
  const int m0 = blockIdx.x * 64;
  // stage x tile (64x256 f32) -> bf16 LDS, coalesced float4 loads
  for (int i = 0; i < 16; ++i) {
    int f = tid + 256 * i;
    int r = f >> 6, c4 = f & 63;
    float4 v = reinterpret_cast<const float4*>(x)[(size_t)(m0 + r) * 64 + c4];
    short4 s4;
    s4.x = f2bf(v.x); s4.y = f2bf(v.y); s4.z = f2bf(v.z); s4.w = f2bf(v.w);
    *reinterpret_cast<short4*>(&xt[r][c4 * 4]) = s4;
  }
  __syncthreads();
  const int w = tid >> 6, l = tid & 63, lr = l & 15, lg = l >> 4;
  bf16x8 af[8];
  #pragma unroll
  for (int kc = 0; kc < 8; ++kc)
    af[kc] = *reinterpret_cast<const bf16x8*>(&xt[w * 16 + lr][kc * 32 + lg * 8]);

  const short* WTs[3] = {WqT, WkT, WvT};
  for (int wi = 0; wi < 3; ++wi) {
    const short* Wt = WTs[wi];
    #pragma unroll 4
    for (int nt = 0; nt < 16; ++nt) {
      f32x4 acc = {0.f, 0.f, 0.f, 0.f};
      #pragma unroll
      for (int kc = 0; kc < 8; ++kc) {
        bf16x8 bfr = *reinterpret_cast<const bf16x8*>(
            &Wt[(nt * 16 + lr) * 256 + kc * 32 + lg * 8]);
        acc = mfma16(af[kc], bfr, acc);
      }
      int colb = nt * 16 + lr;     // D-frag: col = lane&15
      int h = colb >> 5, d = colb & 31;
      #pragma unroll
      for (int r = 0; r < 4; ++r) {  // D-frag: row = (lane>>4)*4 + r
        int m = m0 + w * 16 + lg * 4 + r;
        int b = m >> 10, n = m & 1023;
        short val = f2bf(acc[r]);
        if (wi == 0)
          Q[((size_t)(b * 8 + h) * 1024 + n) * 32 + d] = val;
        else if (wi == 1)
          K[((size_t)(b * 8 + h) * 1024 + n) * 32 + d] = val;
        else
          Vt[((size_t)(b * 8 + h) * 32 + d) * 1024 + n] = val;
      }
    }
  }
}

// ---------------- kernel 2: flash attention with rel-pos bias ----------------
// Block = (b, h, 64 q-rows); 4 waves, wave = 16 q-rows; KV step 32.
// scores = (Q K^T) * scale + bias[h][i][j], softmax over j, O = P V.
__global__ __launch_bounds__(256) void k_attn(const short* __restrict__ Q,
    const short* __restrict__ K, const short* __restrict__ Vt,
    const float* __restrict__ bias_table, short* __restrict__ aout) {
  __shared__ float bias_s[3969];       // bias_table[:, h]
  __shared__ float pbuf[4][16][36];    // per-wave P transpose buffer (D->A layout)
  const int tid = threadIdx.x;
  const int bid = blockIdx.x;
  const int qt = bid & 15, h = (bid >> 4) & 7, b = bid >> 7;
  for (int t = tid; t < 3969; t += 256) bias_s[t] = bias_table[t * 8 + h];
  __syncthreads();
  const int w = tid >> 6, l = tid & 63, lr = l & 15, lg = l >> 4;
  const size_t hoff = (size_t)(b * 8 + h) << 15;  // *1024*32
  const short* Qh = Q + hoff;
  const short* Kh = K + hoff;
  const short* Vh = Vt + hoff;
  const int i0 = qt * 64 + w * 16;
  // Q A-fragment: A[row=lr][k=lg*8+e], full D=32
  bf16x8 qf = *reinterpret_cast<const bf16x8*>(&Qh[(i0 + lr) * 32 + lg * 8]);
  float mr[4], lsum[4];
  f32x4 o0 = {0.f, 0.f, 0.f, 0.f}, o1 = {0.f, 0.f, 0.f, 0.f};
  #pragma unroll
  for (int r = 0; r < 4; ++r) { mr[r] = -1e30f; lsum[r] = 0.f; }
  const float scale = 0.17677669529663688f;  // 1/sqrt(32)
  int yi[4], xi[4];
  #pragma unroll
  for (int r = 0; r < 4; ++r) {
    int i = i0 + lg * 4 + r;
    yi[r] = i >> 5; xi[r] = i & 31;
  }
  #pragma unroll 2
  for (int j0 = 0; j0 < 1024; j0 += 32) {
    // K B-fragments: B[k=d][col=j] = K[j][d] -> contiguous 16B per lane
    bf16x8 kf0 = *reinterpret_cast<const bf16x8*>(&Kh[(j0 + lr) * 32 + lg * 8]);
    bf16x8 kf1 = *reinterpret_cast<const bf16x8*>(&Kh[(j0 + 16 + lr) * 32 + lg * 8]);
    f32x4 z = {0.f, 0.f, 0.f, 0.f};
    f32x4 s0 = mfma16(qf, kf0, z);   // S[i0+row][j0+col]
    f32x4 s1 = mfma16(qf, kf1, z);   // S[i0+row][j0+16+col]
    int ja = j0 + lr, jb = ja + 16;
    int yja = ja >> 5, xja = ja & 31, yjb = jb >> 5, xjb = jb & 31;
    float p0[4], p1[4], mx[4];
    #pragma unroll
    for (int r = 0; r < 4; ++r) {
      float sa = s0[r] * scale + bias_s[(yi[r] - yja + 31) * 63 + (xi[r] - xja + 31)];
      float sb = s1[r] * scale + bias_s[(yi[r] - yjb + 31) * 63 + (xi[r] - xjb + 31)];
      p0[r] = sa; p1[r] = sb;
      float m2 = fmaxf(sa, sb);
      m2 = fmaxf(m2, __shfl_xor(m2, 1));
      m2 = fmaxf(m2, __shfl_xor(m2, 2));
      m2 = fmaxf(m2, __shfl_xor(m2, 4));
      m2 = fmaxf(m2, __shfl_xor(m2, 8));
      mx[r] = m2;
    }
    #pragma unroll
    for (int r = 0; r < 4; ++r) {
      float mn = fmaxf(mr[r], mx[r]);
      float alpha = __expf(mr[r] - mn);
      mr[r] = mn;
      p0[r] = __expf(p0[r] - mn);
      p1[r] = __expf(p1[r] - mn);
      float ps = p0[r] + p1[r];
      ps += __shfl_xor(ps, 1);
      ps += __shfl_xor(ps, 2);
      ps += __shfl_xor(ps, 4);
      ps += __shfl_xor(ps, 8);
      lsum[r] = lsum[r] * alpha + ps;
      o0[r] *= alpha;
      o1[r] *= alpha;
      // D-layout -> LDS: P[row=lg*4+r][col]
      pbuf[w][lg * 4 + r][lr]      = p0[r];
      pbuf[w][lg * 4 + r][16 + lr] = p1[r];
    }
    // read back as A-fragment: P[row=lr][k=lg*8+e] (same wave; compiler waits)
    float4 paf0 = *reinterpret_cast<const float4*>(&pbuf[w][lr][lg * 8]);
    float4 paf1 = *reinterpret_cast<const float4*>(&pbuf[w][lr][lg * 8 + 4]);
    bf16x8 pa;
    pa[0] = f2bf(paf0.x); pa[1] = f2bf(paf0.y);
    pa[2] = f2bf(paf0.z); pa[3] = f2bf(paf0.w);
    pa[4] = f2bf(paf1.x); pa[5] = f2bf(paf1.y);
    pa[6] = f2bf(paf1.z); pa[7] = f2bf(paf1.w);
    // V B-fragments from transposed V: B[k=j][col=d] = Vt[d][j]
    bf16x8 vf0 = *reinterpret_cast<const bf16x8*>(&Vh[lr * 1024 + j0 + lg * 8]);
    bf16x8 vf1 = *reinterpret_cast<const bf16x8*>(&Vh[(16 + lr) * 1024 + j0 + lg * 8]);
    o0 = mfma16(pa, vf0, o0);
    o1 = mfma16(pa, vf1, o1);
  }
  #pragma unroll
  for (int r = 0; r < 4; ++r) {
    float inv = 1.0f / lsum[r];
    int n = i0 + lg * 4 + r;
    size_t base = ((size_t)b << 18) + (size_t)n * 256 + h * 32;
    aout[base + lr]      = f2bf(o0[r] * inv);
    aout[base + 16 + lr] = f2bf(o1[r] * inv);
  }
}

// ---------------- kernel 3: output projection + bias ----------------
__global__ __launch_bounds__(256) void k_outproj(const short* __restrict__ aout,
    const short* __restrict__ WoT, const float* __restrict__ bo,
    float* __restrict__ out) {
  __shared__ short xt[64][264];
  const int tid = threadIdx.x;
  const int m0 = blockIdx.x * 64;
  for (int i = 0; i < 8; ++i) {
    int f = tid + 256 * i;
    int r = f >> 5, c8 = f & 31;
    *reinterpret_cast<bf16x8*>(&xt[r][c8 * 8]) =
        reinterpret_cast<const bf16x8*>(aout)[(size_t)(m0 + r) * 32 + c8];
  }
  __syncthreads();
  const int w = tid >> 6, l = tid & 63, lr = l & 15, lg = l >> 4;
  bf16x8 af[8];
  #pragma unroll
  for (int kc = 0; kc < 8; ++kc)
    af[kc] = *reinterpret_cast<const bf16x8*>(&xt[w * 16 + lr][kc * 32 + lg * 8]);
  #pragma unroll 4
  for (int nt = 0; nt < 16; ++nt) {
    f32x4 acc = {0.f, 0.f, 0.f, 0.f};
    #pragma unroll
    for (int kc = 0; kc < 8; ++kc) {
      bf16x8 bfr = *reinterpret_cast<const bf16x8*>(
          &WoT[(nt * 16 + lr) * 256 + kc * 32 + lg * 8]);
      acc = mfma16(af[kc], bfr, acc);
    }
    int colb = nt * 16 + lr;
    float bias = bo[colb];
    #pragma unroll
    for (int r = 0; r < 4; ++r) {
      int m = m0 + w * 16 + lg * 4 + r;
      out[(size_t)m * 256 + colb] = acc[r] + bias;
    }
  }
}

extern "C" void kernel_launch(void* const* d_in, const int* in_sizes, int n_in,
                              void* d_out, int out_size, void* d_ws, size_t ws_size,
                              hipStream_t stream) {
  const float* x  = (const float*)d_in[0];
  const float* Wq = (const float*)d_in[1];
  const float* Wk = (const float*)d_in[2];
  const float* Wv = (const float*)d_in[3];
  const float* bt = (const float*)d_in[4];
  const float* Wo = (const float*)d_in[5];
  const float* bo = (const float*)d_in[6];
  float* out = (float*)d_out;
  char* ws = (char*)d_ws;
  short* WqT = (short*)ws;
  short* WkT = WqT + 65536;
  short* WvT = WkT + 65536;
  short* WoT = WvT + 65536;
  short* Qs   = (short*)(ws + 512 * 1024);
  short* Ks   = Qs + (16 * 8 * 1024 * 32);
  short* Vts  = Ks + (16 * 8 * 1024 * 32);
  short* aout = Vts + (16 * 8 * 1024 * 32);
  // needs ~33 MB of workspace
  k_transpose_w<<<256, 256, 0, stream>>>(Wq, WqT);
  k_transpose_w<<<256, 256, 0, stream>>>(Wk, WkT);
  k_transpose_w<<<256, 256, 0, stream>>>(Wv, WvT);
  k_transpose_w<<<256, 256, 0, stream>>>(Wo, WoT);
  k_qkv<<<256, 256, 0, stream>>>(x, WqT, WkT, WvT, Qs, Ks, Vts);
  k_attn<<<2048, 256, 0, stream>>>(Qs, Ks, Vts, bt, aout);
  k_outproj<<<256, 256, 0, stream>>>(aout, WoT, bo, out);
}

// Round 2
// 203.052 us; speedup vs baseline: 1.1629x; 1.1629x over previous
//
#include <hip/hip_runtime.h>

// Swin-style attention: B=16, N=1024 (32x32), H=8, D=32, C=256.
// R1 changes: (a) no-max softmax (scores bounded ~|12|, exp-safe in f32) ->
// removes all per-iter cross-lane reductions; (b) bias precomputed in MFMA
// fragment order (x log2e) -> one vector load per KV step instead of LDS
// gather + index math; (c) wi/nt grid splits for the projection GEMMs.

using f32x4  = __attribute__((ext_vector_type(4))) float;
using bf16x8 = __attribute__((ext_vector_type(8))) short;

__device__ __forceinline__ short f2bf(float f) {
  union { float f; unsigned u; } v; v.f = f;
  return (short)((v.u + 0x7FFFu + ((v.u >> 16) & 1u)) >> 16);  // RNE
}
__device__ __forceinline__ float bf2f(short s) {
  union { unsigned u; float f; } v; v.u = ((unsigned)(unsigned short)s) << 16;
  return v.f;
}
__device__ __forceinline__ f32x4 mfma16(bf16x8 a, bf16x8 b, f32x4 c) {
  return __builtin_amdgcn_mfma_f32_16x16x32_bf16(a, b, c, 0, 0, 0);
}

// ---------------- kernel 0: all 4 weight transposes + bf16 cast ----------------
__global__ __launch_bounds__(256) void k_transpose_w(const float* __restrict__ Wq,
    const float* __restrict__ Wk, const float* __restrict__ Wv,
    const float* __restrict__ Wo, short* __restrict__ WT) {
  int wid = blockIdx.x >> 8, n = blockIdx.x & 255, k = threadIdx.x;
  const float* W = wid == 0 ? Wq : wid == 1 ? Wk : wid == 2 ? Wv : Wo;
  WT[wid * 65536 + n * 256 + k] = f2bf(W[k * 256 + n]);
}

// ---------------- kernel 0b: bias table -> MFMA fragment order ----------------
// layout [h][it(64)][jstep(32)][lane(64)][8], values = bias * log2e.
// frag elem e: r=e&3, half=e>>2; i=it*16+lg*4+r; j=jstep*32+half*16+lr.
template <typename DT>
__global__ __launch_bounds__(256) void k_bias(const float* __restrict__ bt,
                                              DT* __restrict__ bf) {
  const float L2E = 1.4426950408889634f;
  int t = blockIdx.x * 256 + threadIdx.x;
  int lane = t & 63, js = (t >> 6) & 31, it = (t >> 11) & 63, h = t >> 17;
  int lr = lane & 15, lg = lane >> 4;
  float v[8];
  #pragma unroll
  for (int e = 0; e < 8; ++e) {
    int r = e & 3, hf = e >> 2;
    int i = it * 16 + lg * 4 + r;
    int j = js * 32 + hf * 16 + lr;
    int idx = ((i >> 5) - (j >> 5) + 31) * 63 + ((i & 31) - (j & 31) + 31);
    v[e] = bt[idx * 8 + h] * L2E;
  }
  if constexpr (sizeof(DT) == 4) {
    float4* p = reinterpret_cast<float4*>(bf + (size_t)t * 8);
    p[0] = make_float4(v[0], v[1], v[2], v[3]);
    p[1] = make_float4(v[4], v[5], v[6], v[7]);
  } else {
    bf16x8 o;
    #pragma unroll
    for (int e = 0; e < 8; ++e) o[e] = f2bf(v[e]);
    *reinterpret_cast<bf16x8*>(bf + (size_t)t * 8) = o;
  }
}

// ---------------- kernel 1: QKV projection (wi = blockIdx.y) ----------------
__global__ __launch_bounds__(256) void k_qkv(const float* __restrict__ x,
    const short* __restrict__ WT,
    short* __restrict__ Q, short* __restrict__ K, short* __restrict__ Vt) {
  __shared__ short xt[64][264];
  const int tid = threadIdx.x;
  const int m0 = blockIdx.x * 64;
  const int wi = blockIdx.y;
  const short* Wt = WT + wi * 65536;
  for (int i = 0; i < 16; ++i) {
    int f = tid + 256 * i;
    int r = f >> 6, c4 = f & 63;
    float4 v = reinterpret_cast<const float4*>(x)[(size_t)(m0 + r) * 64 + c4];
    short4 s4;
    s4.x = f2bf(v.x); s4.y = f2bf(v.y); s4.z = f2bf(v.z); s4.w = f2bf(v.w);
    *reinterpret_cast<short4*>(&xt[r][c4 * 4]) = s4;
  }
  __syncthreads();
  const int w = tid >> 6, l = tid & 63, lr = l & 15, lg = l >> 4;
  bf16x8 af[8];
  #pragma unroll
  for (int kc = 0; kc < 8; ++kc)
    af[kc] = *reinterpret_cast<const bf16x8*>(&xt[w * 16 + lr][kc * 32 + lg * 8]);
  #pragma unroll 4
  for (int nt = 0; nt < 16; ++nt) {
    f32x4 acc = {0.f, 0.f, 0.f, 0.f};
    #pragma unroll
    for (int kc = 0; kc < 8; ++kc) {
      bf16x8 bfr = *reinterpret_cast<const bf16x8*>(
          &Wt[(nt * 16 + lr) * 256 + kc * 32 + lg * 8]);
      acc = mfma16(af[kc], bfr, acc);
    }
    int colb = nt * 16 + lr;
    int h = colb >> 5, d = colb & 31;
    #pragma unroll
    for (int r = 0; r < 4; ++r) {
      int m = m0 + w * 16 + lg * 4 + r;
      int b = m >> 10, n = m & 1023;
      short val = f2bf(acc[r]);
      if (wi == 0)
        Q[((size_t)(b * 8 + h) * 1024 + n) * 32 + d] = val;
      else if (wi == 1)
        K[((size_t)(b * 8 + h) * 1024 + n) * 32 + d] = val;
      else
        Vt[((size_t)(b * 8 + h) * 32 + d) * 1024 + n] = val;
    }
  }
}

// ---------------- kernel 2: flash attention, no-max softmax ----------------
template <typename DT>
__global__ __launch_bounds__(256) void k_attn(const short* __restrict__ Q,
    const short* __restrict__ K, const short* __restrict__ Vt,
    const DT* __restrict__ biasF, short* __restrict__ aout) {
  __shared__ float pbuf[4][16][36];
  const int tid = threadIdx.x, bid = blockIdx.x;
  const int qt = bid & 15, h = (bid >> 4) & 7, b = bid >> 7;
  const int w = tid >> 6, l = tid & 63, lr = l & 15, lg = l >> 4;
  const size_t hoff = (size_t)(b * 8 + h) << 15;
  const short* Qh = Q + hoff;
  const short* Kh = K + hoff;
  const short* Vh = Vt + hoff;
  const int i0 = qt * 64 + w * 16;
  const int it = qt * 4 + w;
  bf16x8 qf = *reinterpret_cast<const bf16x8*>(&Qh[(i0 + lr) * 32 + lg * 8]);
  const DT* bp = biasF + (((size_t)(h * 64 + it) * 32) * 64 + l) * 8;
  f32x4 o0 = {0.f, 0.f, 0.f, 0.f}, o1 = {0.f, 0.f, 0.f, 0.f};
  float ls[4] = {0.f, 0.f, 0.f, 0.f};
  const float cs = 0.17677669529663688f * 1.4426950408889634f;  // scale*log2e
  #pragma unroll 2
  for (int j0 = 0; j0 < 1024; j0 += 32) {
    bf16x8 kf0 = *reinterpret_cast<const bf16x8*>(&Kh[(j0 + lr) * 32 + lg * 8]);
    bf16x8 kf1 = *reinterpret_cast<const bf16x8*>(&Kh[(j0 + 16 + lr) * 32 + lg * 8]);
    f32x4 z = {0.f, 0.f, 0.f, 0.f};
    f32x4 s0 = mfma16(qf, kf0, z);
    f32x4 s1 = mfma16(qf, kf1, z);
    float bv[8];
    if constexpr (sizeof(DT) == 4) {
      float4 ba = *reinterpret_cast<const float4*>(bp);
      float4 bb = *reinterpret_cast<const float4*>(bp + 4);
      bv[0] = ba.x; bv[1] = ba.y; bv[2] = ba.z; bv[3] = ba.w;
      bv[4] = bb.x; bv[5] = bb.y; bv[6] = bb.z; bv[7] = bb.w;
    } else {
      bf16x8 braw = *reinterpret_cast<const bf16x8*>(bp);
      #pragma unroll
      for (int e = 0; e < 8; ++e) bv[e] = bf2f(braw[e]);
    }
    float p0[4], p1[4];
    #pragma unroll
    for (int r = 0; r < 4; ++r) {
      p0[r] = __builtin_amdgcn_exp2f(fmaf(s0[r], cs, bv[r]));
      p1[r] = __builtin_amdgcn_exp2f(fmaf(s1[r], cs, bv[4 + r]));
      ls[r] += p0[r] + p1[r];
      pbuf[w][lg * 4 + r][lr]      = p0[r];
      pbuf[w][lg * 4 + r][16 + lr] = p1[r];
    }
    float4 pa0 = *reinterpret_cast<const float4*>(&pbuf[w][lr][lg * 8]);
    float4 pa1 = *reinterpret_cast<const float4*>(&pbuf[w][lr][lg * 8 + 4]);
    bf16x8 pa;
    pa[0] = f2bf(pa0.x); pa[1] = f2bf(pa0.y);
    pa[2] = f2bf(pa0.z); pa[3] = f2bf(pa0.w);
    pa[4] = f2bf(pa1.x); pa[5] = f2bf(pa1.y);
    pa[6] = f2bf(pa1.z); pa[7] = f2bf(pa1.w);
    bf16x8 vf0 = *reinterpret_cast<const bf16x8*>(&Vh[lr * 1024 + j0 + lg * 8]);
    bf16x8 vf1 = *reinterpret_cast<const bf16x8*>(&Vh[(16 + lr) * 1024 + j0 + lg * 8]);
    o0 = mfma16(pa, vf0, o0);
    o1 = mfma16(pa, vf1, o1);
    bp += 64 * 8;
  }
  #pragma unroll
  for (int r = 0; r < 4; ++r) {
    float s = ls[r];
    s += __shfl_xor(s, 1);
    s += __shfl_xor(s, 2);
    s += __shfl_xor(s, 4);
    s += __shfl_xor(s, 8);
    float inv = 1.0f / s;
    int n = i0 + lg * 4 + r;
    size_t base = ((size_t)b << 18) + (size_t)n * 256 + h * 32;
    aout[base + lr]      = f2bf(o0[r] * inv);
    aout[base + 16 + lr] = f2bf(o1[r] * inv);
  }
}

// ---------------- kernel 3: output projection + bias (nt split) ----------------
__global__ __launch_bounds__(256) void k_outproj(const short* __restrict__ aout,
    const short* __restrict__ WoT, const float* __restrict__ bo,
    float* __restrict__ out) {
  __shared__ short xt[64][264];
  const int tid = threadIdx.x;
  const int m0 = blockIdx.x * 64;
  const int nt0 = blockIdx.y * 8;
  for (int i = 0; i < 8; ++i) {
    int f = tid + 256 * i;
    int r = f >> 5, c8 = f & 31;
    *reinterpret_cast<bf16x8*>(&xt[r][c8 * 8]) =
        reinterpret_cast<const bf16x8*>(aout)[(size_t)(m0 + r) * 32 + c8];
  }
  __syncthreads();
  const int w = tid >> 6, l = tid & 63, lr = l & 15, lg = l >> 4;
  bf16x8 af[8];
  #pragma unroll
  for (int kc = 0; kc < 8; ++kc)
    af[kc] = *reinterpret_cast<const bf16x8*>(&xt[w * 16 + lr][kc * 32 + lg * 8]);
  #pragma unroll 4
  for (int nt = nt0; nt < nt0 + 8; ++nt) {
    f32x4 acc = {0.f, 0.f, 0.f, 0.f};
    #pragma unroll
    for (int kc = 0; kc < 8; ++kc) {
      bf16x8 bfr = *reinterpret_cast<const bf16x8*>(
          &WoT[(nt * 16 + lr) * 256 + kc * 32 + lg * 8]);
      acc = mfma16(af[kc], bfr, acc);
    }
    int colb = nt * 16 + lr;
    float bias = bo[colb];
    #pragma unroll
    for (int r = 0; r < 4; ++r) {
      int m = m0 + w * 16 + lg * 4 + r;
      out[(size_t)m * 256 + colb] = acc[r] + bias;
    }
  }
}

extern "C" void kernel_launch(void* const* d_in, const int* in_sizes, int n_in,
                              void* d_out, int out_size, void* d_ws, size_t ws_size,
                              hipStream_t stream) {
  const float* x  = (const float*)d_in[0];
  const float* Wq = (const float*)d_in[1];
  const float* Wk = (const float*)d_in[2];
  const float* Wv = (const float*)d_in[3];
  const float* bt = (const float*)d_in[4];
  const float* Wo = (const float*)d_in[5];
  const float* bo = (const float*)d_in[6];
  float* out = (float*)d_out;
  char* ws = (char*)d_ws;
  short* WT   = (short*)ws;                          // 4 x 65536 shorts = 512 KB
  short* Qs   = (short*)(ws + 512 * 1024);           // 8 MB each
  short* Ks   = Qs + 4194304;
  short* Vts  = Ks + 4194304;
  short* aout = Vts + 4194304;
  char* bias_base = ws + 512 * 1024 + 4ull * 8388608;  // 34,078,720
  const size_t bias_elems = 8ull * 64 * 32 * 64 * 8;   // 8,388,608
  const size_t need_f32 = 34078720ull + bias_elems * 4;

  k_transpose_w<<<1024, 256, 0, stream>>>(Wq, Wk, Wv, Wo, WT);
  k_qkv<<<dim3(256, 3), 256, 0, stream>>>(x, WT, Qs, Ks, Vts);
  if (ws_size >= need_f32) {
    float* biasF = (float*)bias_base;
    k_bias<float><<<4096, 256, 0, stream>>>(bt, biasF);
    k_attn<float><<<2048, 256, 0, stream>>>(Qs, Ks, Vts, biasF, aout);
  } else {
    short* biasB = (short*)bias_base;
    k_bias<short><<<4096, 256, 0, stream>>>(bt, biasB);
    k_attn<short><<<2048, 256, 0, stream>>>(Qs, Ks, Vts, biasB, aout);
  }
  k_outproj<<<dim3(256, 2), 256, 0, stream>>>(aout, WT + 3 * 65536, bo, out);
}

// Round 4
// 201.403 us; speedup vs baseline: 1.1725x; 1.0082x over previous
//
#include <hip/hip_runtime.h>

// Swin-style attention: B=16, N=1024 (32x32), H=8, D=32, C=256.
// R3: same as R2 design but PV uses the verified 16x16x32 MFMA with a
// permuted contraction axis (logical k = lg*8+e <-> phys j = lg*4+(e&3)+16*(e>>2));
// V is stored n-swizzled in k_qkv so PV B-fragments are contiguous 16B loads.
// k_attn uses no LDS; P never leaves registers.

using f32x4  = __attribute__((ext_vector_type(4))) float;
using bf16x8 = __attribute__((ext_vector_type(8))) short;

__device__ __forceinline__ short f2bf(float f) {
  union { float f; unsigned u; } v; v.f = f;
  return (short)((v.u + 0x7FFFu + ((v.u >> 16) & 1u)) >> 16);  // RNE
}
__device__ __forceinline__ float bf2f(short s) {
  union { unsigned u; float f; } v; v.u = ((unsigned)(unsigned short)s) << 16;
  return v.f;
}
__device__ __forceinline__ f32x4 mfma_k32(bf16x8 a, bf16x8 b, f32x4 c) {
  return __builtin_amdgcn_mfma_f32_16x16x32_bf16(a, b, c, 0, 0, 0);
}
__device__ __forceinline__ int cvt_pk_bf16(float lo, float hi) {
  int r;
  asm("v_cvt_pk_bf16_f32 %0, %1, %2" : "=v"(r) : "v"(lo), "v"(hi));
  return r;
}

// ---------------- kernel 0: all 4 weight transposes + bf16 cast ----------------
__global__ __launch_bounds__(256) void k_transpose_w(const float* __restrict__ Wq,
    const float* __restrict__ Wk, const float* __restrict__ Wv,
    const float* __restrict__ Wo, short* __restrict__ WT) {
  int wid = blockIdx.x >> 8, n = blockIdx.x & 255, k = threadIdx.x;
  const float* W = wid == 0 ? Wq : wid == 1 ? Wk : wid == 2 ? Wv : Wo;
  WT[wid * 65536 + n * 256 + k] = f2bf(W[k * 256 + n]);
}

// ---------------- kernel 0b: bias -> S^T MFMA fragment order ----------------
// layout [h][it(64)][js(32)][lane(64)][8], value = bias * log2e.
// elem e: r=e&3, sel=e>>2; i = it*16 + lr; j = js*32 + sel*16 + lg*4 + r.
template <typename DT>
__global__ __launch_bounds__(256) void k_bias(const float* __restrict__ bt,
                                              DT* __restrict__ bf) {
  const float L2E = 1.4426950408889634f;
  int t = blockIdx.x * 256 + threadIdx.x;
  int lane = t & 63, js = (t >> 6) & 31, it = (t >> 11) & 63, h = t >> 17;
  int lr = lane & 15, lg = lane >> 4;
  float v[8];
  #pragma unroll
  for (int e = 0; e < 8; ++e) {
    int r = e & 3, sel = e >> 2;
    int i = it * 16 + lr;
    int j = js * 32 + sel * 16 + lg * 4 + r;
    int idx = ((i >> 5) - (j >> 5) + 31) * 63 + ((i & 31) - (j & 31) + 31);
    v[e] = bt[idx * 8 + h] * L2E;
  }
  if constexpr (sizeof(DT) == 4) {
    float4* p = reinterpret_cast<float4*>(bf + (size_t)t * 8);
    p[0] = make_float4(v[0], v[1], v[2], v[3]);
    p[1] = make_float4(v[4], v[5], v[6], v[7]);
  } else {
    bf16x8 o;
    #pragma unroll
    for (int e = 0; e < 8; ++e) o[e] = f2bf(v[e]);
    *reinterpret_cast<bf16x8*>(bf + (size_t)t * 8) = o;
  }
}

// ---------------- kernel 1: QKV projection (wi = blockIdx.y) ----------------
// V stored n-swizzled: within each 32-block of n, position p = lgv*8 + hi*4 + r
// holds phys n = lgv*4 + r + 16*hi  (lgv=(n&15)>>2, hi=(n>>4)&1, r=n&3).
__global__ __launch_bounds__(256) void k_qkv(const float* __restrict__ x,
    const short* __restrict__ WT,
    short* __restrict__ Q, short* __restrict__ K, short* __restrict__ Vt) {
  __shared__ short xt[64][264];
  const int tid = threadIdx.x;
  const int m0 = blockIdx.x * 64;
  const int wi = blockIdx.y;
  const short* Wt = WT + wi * 65536;
  for (int i = 0; i < 16; ++i) {
    int f = tid + 256 * i;
    int r = f >> 6, c4 = f & 63;
    float4 v = reinterpret_cast<const float4*>(x)[(size_t)(m0 + r) * 64 + c4];
    short4 s4;
    s4.x = f2bf(v.x); s4.y = f2bf(v.y); s4.z = f2bf(v.z); s4.w = f2bf(v.w);
    *reinterpret_cast<short4*>(&xt[r][c4 * 4]) = s4;
  }
  __syncthreads();
  const int w = tid >> 6, l = tid & 63, lr = l & 15, lg = l >> 4;
  bf16x8 af[8];
  #pragma unroll
  for (int kc = 0; kc < 8; ++kc)
    af[kc] = *reinterpret_cast<const bf16x8*>(&xt[w * 16 + lr][kc * 32 + lg * 8]);
  #pragma unroll 4
  for (int nt = 0; nt < 16; ++nt) {
    f32x4 acc = {0.f, 0.f, 0.f, 0.f};
    #pragma unroll
    for (int kc = 0; kc < 8; ++kc) {
      bf16x8 bfr = *reinterpret_cast<const bf16x8*>(
          &Wt[(nt * 16 + lr) * 256 + kc * 32 + lg * 8]);
      acc = mfma_k32(af[kc], bfr, acc);
    }
    int colb = nt * 16 + lr;
    int h = colb >> 5, d = colb & 31;
    if (wi == 2) {
      int m = m0 + w * 16 + lg * 4;  // 4 consecutive n (r=0..3)
      int b = m >> 10, n0 = m & 1023;
      int jblk = n0 & ~31;
      int lgv = (n0 & 15) >> 2, hi = (n0 >> 4) & 1;
      int p = jblk + lgv * 8 + hi * 4;
      short4 vv;
      vv.x = f2bf(acc[0]); vv.y = f2bf(acc[1]);
      vv.z = f2bf(acc[2]); vv.w = f2bf(acc[3]);
      *reinterpret_cast<short4*>(&Vt[((size_t)(b * 8 + h) * 32 + d) * 1024 + p]) = vv;
    } else {
      #pragma unroll
      for (int r = 0; r < 4; ++r) {
        int m = m0 + w * 16 + lg * 4 + r;
        int b = m >> 10, n = m & 1023;
        short val = f2bf(acc[r]);
        if (wi == 0)
          Q[((size_t)(b * 8 + h) * 1024 + n) * 32 + d] = val;
        else
          K[((size_t)(b * 8 + h) * 1024 + n) * 32 + d] = val;
      }
    }
  }
}

// ---------------- kernel 2: flash attention, S^T layout, no LDS ----------------
template <typename DT>
__global__ __launch_bounds__(256) void k_attn(const short* __restrict__ Q,
    const short* __restrict__ K, const short* __restrict__ Vt,
    const DT* __restrict__ biasF, short* __restrict__ aout) {
  const int tid = threadIdx.x, bid = blockIdx.x;
  // h in low 3 bits: round-robin XCD assignment gives each XCD one head's
  // K/V + bias slice -> L2-resident working set.
  const int h = bid & 7, qt = (bid >> 3) & 15, b = bid >> 7;
  const int w = tid >> 6, l = tid & 63, lr = l & 15, lg = l >> 4;
  const size_t hoff = (size_t)(b * 8 + h) << 15;
  const short* Qh = Q + hoff;
  const short* Kh = K + hoff;
  const short* Vh = Vt + hoff;
  const int i0 = qt * 64 + w * 16;
  const int it = qt * 4 + w;
  // Q as B-fragment: B[k=d][col=i-i0] = Q[i0+col][d]
  bf16x8 qf = *reinterpret_cast<const bf16x8*>(&Qh[(i0 + lr) * 32 + lg * 8]);
  const DT* bp = biasF + (((size_t)(h * 64 + it) * 32) * 64 + l) * 8;
  f32x4 o0 = {0.f, 0.f, 0.f, 0.f}, o1 = {0.f, 0.f, 0.f, 0.f};
  float ls = 0.f;
  const float cs = 0.17677669529663688f * 1.4426950408889634f;  // scale*log2e
  #pragma unroll 2
  for (int j0 = 0; j0 < 1024; j0 += 32) {
    // K as A-fragment: A[row=j-j0][k=d] = K[j0+row][d]
    bf16x8 kf0 = *reinterpret_cast<const bf16x8*>(&Kh[(j0 + lr) * 32 + lg * 8]);
    bf16x8 kf1 = *reinterpret_cast<const bf16x8*>(&Kh[(j0 + 16 + lr) * 32 + lg * 8]);
    f32x4 z = {0.f, 0.f, 0.f, 0.f};
    f32x4 s0 = mfma_k32(kf0, qf, z);  // S^T: lane holds S[i0+lr][j0+lg*4+r]
    f32x4 s1 = mfma_k32(kf1, qf, z);  // S[i0+lr][j0+16+lg*4+r]
    float bv[8];
    if constexpr (sizeof(DT) == 4) {
      float4 ba = *reinterpret_cast<const float4*>(bp);
      float4 bb = *reinterpret_cast<const float4*>(bp + 4);
      bv[0] = ba.x; bv[1] = ba.y; bv[2] = ba.z; bv[3] = ba.w;
      bv[4] = bb.x; bv[5] = bb.y; bv[6] = bb.z; bv[7] = bb.w;
    } else {
      bf16x8 braw = *reinterpret_cast<const bf16x8*>(bp);
      #pragma unroll
      for (int e = 0; e < 8; ++e) bv[e] = bf2f(braw[e]);
    }
    float p0[4], p1[4];
    #pragma unroll
    for (int r = 0; r < 4; ++r) {
      p0[r] = __builtin_amdgcn_exp2f(fmaf(s0[r], cs, bv[r]));
      p1[r] = __builtin_amdgcn_exp2f(fmaf(s1[r], cs, bv[4 + r]));
      ls += p0[r] + p1[r];  // partial row-sum for row i0+lr
    }
    // P as K=32 A-fragment under permuted k-axis:
    // elem e (k=lg*8+e) <-> phys j = j0 + lg*4 + (e&3) + 16*(e>>2).
    union { int i4[4]; bf16x8 v; } pk;
    pk.i4[0] = cvt_pk_bf16(p0[0], p0[1]);
    pk.i4[1] = cvt_pk_bf16(p0[2], p0[3]);
    pk.i4[2] = cvt_pk_bf16(p1[0], p1[1]);
    pk.i4[3] = cvt_pk_bf16(p1[2], p1[3]);
    // V B-fragment: Vt is n-swizzled to match the same permutation ->
    // contiguous 16B per lane at [d][j0 + lg*8].
    bf16x8 vf0 = *reinterpret_cast<const bf16x8*>(&Vh[lr * 1024 + j0 + lg * 8]);
    bf16x8 vf1 = *reinterpret_cast<const bf16x8*>(&Vh[(16 + lr) * 1024 + j0 + lg * 8]);
    o0 = mfma_k32(pk.v, vf0, o0);  // O[i=i0+lg*4+r][d=lr]
    o1 = mfma_k32(pk.v, vf1, o1);  // O[i][d=16+lr]
    bp += 64 * 8;
  }
  // full row-sum for row i0+lr: reduce partials across the 4 lane-groups
  float s = ls + __shfl_xor(ls, 16);
  s += __shfl_xor(s, 32);
  float inv = 1.0f / s;
  #pragma unroll
  for (int r = 0; r < 4; ++r) {
    float invr = __shfl(inv, lg * 4 + r);  // sum for row i0+lg*4+r
    int n = i0 + lg * 4 + r;
    size_t base = ((size_t)b << 18) + (size_t)n * 256 + h * 32;
    aout[base + lr]      = f2bf(o0[r] * invr);
    aout[base + 16 + lr] = f2bf(o1[r] * invr);
  }
}

// ---------------- kernel 3: output projection + bias (nt split) ----------------
__global__ __launch_bounds__(256) void k_outproj(const short* __restrict__ aout,
    const short* __restrict__ WoT, const float* __restrict__ bo,
    float* __restrict__ out) {
  __shared__ short xt[64][264];
  const int tid = threadIdx.x;
  const int m0 = blockIdx.x * 64;
  const int nt0 = blockIdx.y * 8;
  for (int i = 0; i < 8; ++i) {
    int f = tid + 256 * i;
    int r = f >> 5, c8 = f & 31;
    *reinterpret_cast<bf16x8*>(&xt[r][c8 * 8]) =
        reinterpret_cast<const bf16x8*>(aout)[(size_t)(m0 + r) * 32 + c8];
  }
  __syncthreads();
  const int w = tid >> 6, l = tid & 63, lr = l & 15, lg = l >> 4;
  bf16x8 af[8];
  #pragma unroll
  for (int kc = 0; kc < 8; ++kc)
    af[kc] = *reinterpret_cast<const bf16x8*>(&xt[w * 16 + lr][kc * 32 + lg * 8]);
  #pragma unroll 4
  for (int nt = nt0; nt < nt0 + 8; ++nt) {
    f32x4 acc = {0.f, 0.f, 0.f, 0.f};
    #pragma unroll
    for (int kc = 0; kc < 8; ++kc) {
      bf16x8 bfr = *reinterpret_cast<const bf16x8*>(
          &WoT[(nt * 16 + lr) * 256 + kc * 32 + lg * 8]);
      acc = mfma_k32(af[kc], bfr, acc);
    }
    int colb = nt * 16 + lr;
    float bias = bo[colb];
    #pragma unroll
    for (int r = 0; r < 4; ++r) {
      int m = m0 + w * 16 + lg * 4 + r;
      out[(size_t)m * 256 + colb] = acc[r] + bias;
    }
  }
}

extern "C" void kernel_launch(void* const* d_in, const int* in_sizes, int n_in,
                              void* d_out, int out_size, void* d_ws, size_t ws_size,
                              hipStream_t stream) {
  const float* x  = (const float*)d_in[0];
  const float* Wq = (const float*)d_in[1];
  const float* Wk = (const float*)d_in[2];
  const float* Wv = (const float*)d_in[3];
  const float* bt = (const float*)d_in[4];
  const float* Wo = (const float*)d_in[5];
  const float* bo = (const float*)d_in[6];
  float* out = (float*)d_out;
  char* ws = (char*)d_ws;
  short* WT   = (short*)ws;                          // 4 x 65536 shorts = 512 KB
  short* Qs   = (short*)(ws + 512 * 1024);           // 8 MB each
  short* Ks   = Qs + 4194304;
  short* Vts  = Ks + 4194304;
  short* aout = Vts + 4194304;
  char* bias_base = ws + 512 * 1024 + 4ull * 8388608;  // 34,078,720
  const size_t bias_elems = 8ull * 64 * 32 * 64 * 8;   // 8,388,608
  const size_t need_f32 = 34078720ull + bias_elems * 4;

  k_transpose_w<<<1024, 256, 0, stream>>>(Wq, Wk, Wv, Wo, WT);
  k_qkv<<<dim3(256, 3), 256, 0, stream>>>(x, WT, Qs, Ks, Vts);
  if (ws_size >= need_f32) {
    float* biasF = (float*)bias_base;
    k_bias<float><<<4096, 256, 0, stream>>>(bt, biasF);
    k_attn<float><<<2048, 256, 0, stream>>>(Qs, Ks, Vts, biasF, aout);
  } else {
    short* biasB = (short*)bias_base;
    k_bias<short><<<4096, 256, 0, stream>>>(bt, biasB);
    k_attn<short><<<2048, 256, 0, stream>>>(Qs, Ks, Vts, biasB, aout);
  }
  k_outproj<<<dim3(256, 2), 256, 0, stream>>>(aout, WT + 3 * 65536, bo, out);
}

// Round 6
// 171.611 us; speedup vs baseline: 1.3760x; 1.1736x over previous
//
#include <hip/hip_runtime.h>

// Swin-style attention: B=16, N=1024 (32x32), H=8, D=32, C=256.
// R5 (bisect of R4): exactly R3's k_attn structure (grid 2048, one i-tile per
// wave, h in low grid bits) with ONLY the bias source changed: compact
// per-head 63x63 table (x log2e) staged in LDS, row-gathered per j-block.
// Kills the 32MB fragment-bias stream that dominated k_attn's time.

using f32x4  = __attribute__((ext_vector_type(4))) float;
using bf16x8 = __attribute__((ext_vector_type(8))) short;

__device__ __forceinline__ short f2bf(float f) {
  union { float f; unsigned u; } v; v.f = f;
  return (short)((v.u + 0x7FFFu + ((v.u >> 16) & 1u)) >> 16);  // RNE
}
__device__ __forceinline__ f32x4 mfma_k32(bf16x8 a, bf16x8 b, f32x4 c) {
  return __builtin_amdgcn_mfma_f32_16x16x32_bf16(a, b, c, 0, 0, 0);
}
__device__ __forceinline__ int cvt_pk_bf16(float lo, float hi) {
  int r;
  asm("v_cvt_pk_bf16_f32 %0, %1, %2" : "=v"(r) : "v"(lo), "v"(hi));
  return r;
}

// ---------------- kernel 0: all 4 weight transposes + bf16 cast ----------------
__global__ __launch_bounds__(256) void k_transpose_w(const float* __restrict__ Wq,
    const float* __restrict__ Wk, const float* __restrict__ Wv,
    const float* __restrict__ Wo, short* __restrict__ WT) {
  int wid = blockIdx.x >> 8, n = blockIdx.x & 255, k = threadIdx.x;
  const float* W = wid == 0 ? Wq : wid == 1 ? Wk : wid == 2 ? Wv : Wo;
  WT[wid * 65536 + n * 256 + k] = f2bf(W[k * 256 + n]);
}

// ---------------- kernel 0b: bias table -> [h][4096] row-major, x log2e --------
__global__ __launch_bounds__(256) void k_bias(const float* __restrict__ bt,
                                              float* __restrict__ Tg) {
  int idx = blockIdx.x * 256 + threadIdx.x;  // 128 blocks x 256 = 8 x 4096
  int h = idx >> 12, i = idx & 4095;
  if (i < 3969) Tg[idx] = bt[i * 8 + h] * 1.4426950408889634f;
}

// ---------------- kernel 1: QKV projection (wi = blockIdx.y) ----------------
// V stored n-swizzled: within each 32-block of n, position p = lgv*8 + hi*4 + r
// holds phys n = lgv*4 + r + 16*hi.
__global__ __launch_bounds__(256) void k_qkv(const float* __restrict__ x,
    const short* __restrict__ WT,
    short* __restrict__ Q, short* __restrict__ K, short* __restrict__ Vt) {
  __shared__ short xt[64][264];
  const int tid = threadIdx.x;
  const int m0 = blockIdx.x * 64;
  const int wi = blockIdx.y;
  const short* Wt = WT + wi * 65536;
  for (int i = 0; i < 16; ++i) {
    int f = tid + 256 * i;
    int r = f >> 6, c4 = f & 63;
    float4 v = reinterpret_cast<const float4*>(x)[(size_t)(m0 + r) * 64 + c4];
    short4 s4;
    s4.x = f2bf(v.x); s4.y = f2bf(v.y); s4.z = f2bf(v.z); s4.w = f2bf(v.w);
    *reinterpret_cast<short4*>(&xt[r][c4 * 4]) = s4;
  }
  __syncthreads();
  const int w = tid >> 6, l = tid & 63, lr = l & 15, lg = l >> 4;
  bf16x8 af[8];
  #pragma unroll
  for (int kc = 0; kc < 8; ++kc)
    af[kc] = *reinterpret_cast<const bf16x8*>(&xt[w * 16 + lr][kc * 32 + lg * 8]);
  #pragma unroll 4
  for (int nt = 0; nt < 16; ++nt) {
    f32x4 acc = {0.f, 0.f, 0.f, 0.f};
    #pragma unroll
    for (int kc = 0; kc < 8; ++kc) {
      bf16x8 bfr = *reinterpret_cast<const bf16x8*>(
          &Wt[(nt * 16 + lr) * 256 + kc * 32 + lg * 8]);
      acc = mfma_k32(af[kc], bfr, acc);
    }
    int colb = nt * 16 + lr;
    int h = colb >> 5, d = colb & 31;
    if (wi == 2) {
      int m = m0 + w * 16 + lg * 4;  // 4 consecutive n (r=0..3)
      int b = m >> 10, n0 = m & 1023;
      int jblk = n0 & ~31;
      int lgv = (n0 & 15) >> 2, hi = (n0 >> 4) & 1;
      int p = jblk + lgv * 8 + hi * 4;
      short4 vv;
      vv.x = f2bf(acc[0]); vv.y = f2bf(acc[1]);
      vv.z = f2bf(acc[2]); vv.w = f2bf(acc[3]);
      *reinterpret_cast<short4*>(&Vt[((size_t)(b * 8 + h) * 32 + d) * 1024 + p]) = vv;
    } else {
      #pragma unroll
      for (int r = 0; r < 4; ++r) {
        int m = m0 + w * 16 + lg * 4 + r;
        int b = m >> 10, n = m & 1023;
        short val = f2bf(acc[r]);
        if (wi == 0)
          Q[((size_t)(b * 8 + h) * 1024 + n) * 32 + d] = val;
        else
          K[((size_t)(b * 8 + h) * 1024 + n) * 32 + d] = val;
      }
    }
  }
}

// ---------------- kernel 2: flash attention, compact LDS bias ----------------
// Block = (b, h, 64 q-rows); 4 waves, wave = one 16-row i-tile. Grid 2048.
__global__ __launch_bounds__(256) void k_attn(const short* __restrict__ Q,
    const short* __restrict__ K, const short* __restrict__ Vt,
    const float* __restrict__ Tg, short* __restrict__ aout) {
  __shared__ float Tlds[3969];  // per-head 63x63 bias table (x log2e)
  const int tid = threadIdx.x, bid = blockIdx.x;
  const int h = bid & 7, qt = (bid >> 3) & 15, b = bid >> 7;
  const float* Th = Tg + (h << 12);
  for (int t = tid; t < 3969; t += 256) Tlds[t] = Th[t];
  __syncthreads();
  const int w = tid >> 6, l = tid & 63, lr = l & 15, lg = l >> 4;
  const size_t hoff = (size_t)(b * 8 + h) << 15;
  const short* Qh = Q + hoff;
  const short* Kh = K + hoff;
  const short* Vh = Vt + hoff;
  const int it = qt * 4 + w;
  const int i0 = it * 16;
  const int yi = it >> 1;                                 // i0 step 16: y = it/2
  const int pbase = ((it & 1) << 4) + lr - lg * 4 + 31;   // x_i - x_j0 + 31 base
  // Q as B-fragment: B[k=d][col=i-i0] = Q[i0+col][d]
  bf16x8 qf = *reinterpret_cast<const bf16x8*>(&Qh[(i0 + lr) * 32 + lg * 8]);
  f32x4 o0 = {0.f, 0.f, 0.f, 0.f}, o1 = {0.f, 0.f, 0.f, 0.f};
  float ls = 0.f;
  const float cs = 0.17677669529663688f * 1.4426950408889634f;  // scale*log2e
  #pragma unroll 2
  for (int js = 0; js < 32; ++js) {
    const int j0 = js * 32;
    // K as A-fragment: A[row=j-j0][k=d] = K[j0+row][d]
    bf16x8 kf0 = *reinterpret_cast<const bf16x8*>(&Kh[(j0 + lr) * 32 + lg * 8]);
    bf16x8 kf1 = *reinterpret_cast<const bf16x8*>(&Kh[(j0 + 16 + lr) * 32 + lg * 8]);
    f32x4 z = {0.f, 0.f, 0.f, 0.f};
    f32x4 s0 = mfma_k32(kf0, qf, z);  // S[i0+lr][j0+lg*4+r]
    f32x4 s1 = mfma_k32(kf1, qf, z);  // S[i0+lr][j0+16+lg*4+r]
    // bias row for this j-block: y_j = js, x_j = lg*4+r (+16 for s1)
    const float* Trow = &Tlds[(yi - js + 31) * 63];
    float p0[4], p1[4];
    #pragma unroll
    for (int r = 0; r < 4; ++r) {
      p0[r] = __builtin_amdgcn_exp2f(fmaf(s0[r], cs, Trow[pbase - r]));
      p1[r] = __builtin_amdgcn_exp2f(fmaf(s1[r], cs, Trow[pbase - 16 - r]));
      ls += p0[r] + p1[r];  // partial row-sum for row i0+lr
    }
    // P as K=32 A-fragment under permuted k-axis:
    // elem e (k=lg*8+e) <-> phys j = j0 + lg*4 + (e&3) + 16*(e>>2).
    union { int i4[4]; bf16x8 v; } pk;
    pk.i4[0] = cvt_pk_bf16(p0[0], p0[1]);
    pk.i4[1] = cvt_pk_bf16(p0[2], p0[3]);
    pk.i4[2] = cvt_pk_bf16(p1[0], p1[1]);
    pk.i4[3] = cvt_pk_bf16(p1[2], p1[3]);
    // V B-fragment: Vt n-swizzled to the same permutation -> contiguous 16B.
    bf16x8 vf0 = *reinterpret_cast<const bf16x8*>(&Vh[lr * 1024 + j0 + lg * 8]);
    bf16x8 vf1 = *reinterpret_cast<const bf16x8*>(&Vh[(16 + lr) * 1024 + j0 + lg * 8]);
    o0 = mfma_k32(pk.v, vf0, o0);  // O[i=i0+lg*4+r][d=lr]
    o1 = mfma_k32(pk.v, vf1, o1);  // O[i][d=16+lr]
  }
  // full row-sum for row i0+lr: reduce partials across the 4 lane-groups
  float s = ls + __shfl_xor(ls, 16);
  s += __shfl_xor(s, 32);
  float inv = 1.0f / s;
  #pragma unroll
  for (int r = 0; r < 4; ++r) {
    float invr = __shfl(inv, lg * 4 + r);  // sum for row i0+lg*4+r
    int n = i0 + lg * 4 + r;
    size_t base = ((size_t)b << 18) + (size_t)n * 256 + h * 32;
    aout[base + lr]      = f2bf(o0[r] * invr);
    aout[base + 16 + lr] = f2bf(o1[r] * invr);
  }
}

// ---------------- kernel 3: output projection + bias (nt split) ----------------
__global__ __launch_bounds__(256) void k_outproj(const short* __restrict__ aout,
    const short* __restrict__ WoT, const float* __restrict__ bo,
    float* __restrict__ out) {
  __shared__ short xt[64][264];
  const int tid = threadIdx.x;
  const int m0 = blockIdx.x * 64;
  const int nt0 = blockIdx.y * 8;
  for (int i = 0; i < 8; ++i) {
    int f = tid + 256 * i;
    int r = f >> 5, c8 = f & 31;
    *reinterpret_cast<bf16x8*>(&xt[r][c8 * 8]) =
        reinterpret_cast<const bf16x8*>(aout)[(size_t)(m0 + r) * 32 + c8];
  }
  __syncthreads();
  const int w = tid >> 6, l = tid & 63, lr = l & 15, lg = l >> 4;
  bf16x8 af[8];
  #pragma unroll
  for (int kc = 0; kc < 8; ++kc)
    af[kc] = *reinterpret_cast<const bf16x8*>(&xt[w * 16 + lr][kc * 32 + lg * 8]);
  #pragma unroll 4
  for (int nt = nt0; nt < nt0 + 8; ++nt) {
    f32x4 acc = {0.f, 0.f, 0.f, 0.f};
    #pragma unroll
    for (int kc = 0; kc < 8; ++kc) {
      bf16x8 bfr = *reinterpret_cast<const bf16x8*>(
          &WoT[(nt * 16 + lr) * 256 + kc * 32 + lg * 8]);
      acc = mfma_k32(af[kc], bfr, acc);
    }
    int colb = nt * 16 + lr;
    float bias = bo[colb];
    #pragma unroll
    for (int r = 0; r < 4; ++r) {
      int m = m0 + w * 16 + lg * 4 + r;
      out[(size_t)m * 256 + colb] = acc[r] + bias;
    }
  }
}

extern "C" void kernel_launch(void* const* d_in, const int* in_sizes, int n_in,
                              void* d_out, int out_size, void* d_ws, size_t ws_size,
                              hipStream_t stream) {
  const float* x  = (const float*)d_in[0];
  const float* Wq = (const float*)d_in[1];
  const float* Wk = (const float*)d_in[2];
  const float* Wv = (const float*)d_in[3];
  const float* bt = (const float*)d_in[4];
  const float* Wo = (const float*)d_in[5];
  const float* bo = (const float*)d_in[6];
  float* out = (float*)d_out;
  char* ws = (char*)d_ws;
  short* WT   = (short*)ws;                          // 4 x 65536 shorts = 512 KB
  short* Qs   = (short*)(ws + 512 * 1024);           // 8 MB each
  short* Ks   = Qs + 4194304;
  short* Vts  = Ks + 4194304;
  short* aout = Vts + 4194304;
  float* Tg   = (float*)(ws + 512 * 1024 + 4ull * 8388608);  // 8x4096 f32 = 128 KB

  k_transpose_w<<<1024, 256, 0, stream>>>(Wq, Wk, Wv, Wo, WT);
  k_bias<<<128, 256, 0, stream>>>(bt, Tg);
  k_qkv<<<dim3(256, 3), 256, 0, stream>>>(x, WT, Qs, Ks, Vts);
  k_attn<<<2048, 256, 0, stream>>>(Qs, Ks, Vts, Tg, aout);
  k_outproj<<<dim3(256, 2), 256, 0, stream>>>(aout, WT + 3 * 65536, bo, out);
}

// Round 7
// 144.901 us; speedup vs baseline: 1.6296x; 1.1843x over previous
//
#include <hip/hip_runtime.h>

// Swin-style attention: B=16, N=1024 (32x32), H=8, D=32, C=256.
// R6: (a) V stored as per-j-block fragment-ordered 32x32 subtiles ->
// PV loads hit one contiguous 2KB region (kills L1 set-conflict thrash of
// the old stride-2KB reads); (b) register software-pipeline of next K/V
// fragments across the js loop. Bias: compact per-head 63x63 LDS table (R5).

using f32x4  = __attribute__((ext_vector_type(4))) float;
using bf16x8 = __attribute__((ext_vector_type(8))) short;

__device__ __forceinline__ short f2bf(float f) {
  union { float f; unsigned u; } v; v.f = f;
  return (short)((v.u + 0x7FFFu + ((v.u >> 16) & 1u)) >> 16);  // RNE
}
__device__ __forceinline__ f32x4 mfma_k32(bf16x8 a, bf16x8 b, f32x4 c) {
  return __builtin_amdgcn_mfma_f32_16x16x32_bf16(a, b, c, 0, 0, 0);
}
__device__ __forceinline__ int cvt_pk_bf16(float lo, float hi) {
  int r;
  asm("v_cvt_pk_bf16_f32 %0, %1, %2" : "=v"(r) : "v"(lo), "v"(hi));
  return r;
}

// ---------------- kernel 0: all 4 weight transposes + bf16 cast ----------------
__global__ __launch_bounds__(256) void k_transpose_w(const float* __restrict__ Wq,
    const float* __restrict__ Wk, const float* __restrict__ Wv,
    const float* __restrict__ Wo, short* __restrict__ WT) {
  int wid = blockIdx.x >> 8, n = blockIdx.x & 255, k = threadIdx.x;
  const float* W = wid == 0 ? Wq : wid == 1 ? Wk : wid == 2 ? Wv : Wo;
  WT[wid * 65536 + n * 256 + k] = f2bf(W[k * 256 + n]);
}

// ---------------- kernel 0b: bias table -> [h][4096] row-major, x log2e --------
__global__ __launch_bounds__(256) void k_bias(const float* __restrict__ bt,
                                              float* __restrict__ Tg) {
  int idx = blockIdx.x * 256 + threadIdx.x;  // 128 blocks x 256 = 8 x 4096
  int h = idx >> 12, i = idx & 4095;
  if (i < 3969) Tg[idx] = bt[i * 8 + h] * 1.4426950408889634f;
}

// ---------------- kernel 1: QKV projection (wi = blockIdx.y) ----------------
// V stored as fragment-ordered subtiles: Vf[((b*8+h)*32 + js)*1024 + d*32 + jp]
// where jp = lgv*8 + hi*4 + r encodes phys j = js*32 + lgv*4 + r + 16*hi.
__global__ __launch_bounds__(256) void k_qkv(const float* __restrict__ x,
    const short* __restrict__ WT,
    short* __restrict__ Q, short* __restrict__ K, short* __restrict__ Vt) {
  __shared__ short xt[64][264];
  const int tid = threadIdx.x;
  const int m0 = blockIdx.x * 64;
  const int wi = blockIdx.y;
  const short* Wt = WT + wi * 65536;
  for (int i = 0; i < 16; ++i) {
    int f = tid + 256 * i;
    int r = f >> 6, c4 = f & 63;
    float4 v = reinterpret_cast<const float4*>(x)[(size_t)(m0 + r) * 64 + c4];
    short4 s4;
    s4.x = f2bf(v.x); s4.y = f2bf(v.y); s4.z = f2bf(v.z); s4.w = f2bf(v.w);
    *reinterpret_cast<short4*>(&xt[r][c4 * 4]) = s4;
  }
  __syncthreads();
  const int w = tid >> 6, l = tid & 63, lr = l & 15, lg = l >> 4;
  bf16x8 af[8];
  #pragma unroll
  for (int kc = 0; kc < 8; ++kc)
    af[kc] = *reinterpret_cast<const bf16x8*>(&xt[w * 16 + lr][kc * 32 + lg * 8]);
  #pragma unroll 4
  for (int nt = 0; nt < 16; ++nt) {
    f32x4 acc = {0.f, 0.f, 0.f, 0.f};
    #pragma unroll
    for (int kc = 0; kc < 8; ++kc) {
      bf16x8 bfr = *reinterpret_cast<const bf16x8*>(
          &Wt[(nt * 16 + lr) * 256 + kc * 32 + lg * 8]);
      acc = mfma_k32(af[kc], bfr, acc);
    }
    int colb = nt * 16 + lr;
    int h = colb >> 5, d = colb & 31;
    if (wi == 2) {
      int m = m0 + w * 16 + lg * 4;  // 4 consecutive n (r=0..3)
      int b = m >> 10, n0 = m & 1023;
      int js = n0 >> 5;
      int lgv = (n0 & 15) >> 2, hi = (n0 >> 4) & 1;
      int jp = lgv * 8 + hi * 4;
      short4 vv;
      vv.x = f2bf(acc[0]); vv.y = f2bf(acc[1]);
      vv.z = f2bf(acc[2]); vv.w = f2bf(acc[3]);
      *reinterpret_cast<short4*>(
          &Vt[(((size_t)(b * 8 + h) * 32 + js) << 10) + d * 32 + jp]) = vv;
    } else {
      #pragma unroll
      for (int r = 0; r < 4; ++r) {
        int m = m0 + w * 16 + lg * 4 + r;
        int b = m >> 10, n = m & 1023;
        short val = f2bf(acc[r]);
        if (wi == 0)
          Q[((size_t)(b * 8 + h) * 1024 + n) * 32 + d] = val;
        else
          K[((size_t)(b * 8 + h) * 1024 + n) * 32 + d] = val;
      }
    }
  }
}

// ---------------- kernel 2: flash attention, pipelined ----------------
// Block = (b, h, 64 q-rows); 4 waves, wave = one 16-row i-tile. Grid 2048.
__global__ __launch_bounds__(256) void k_attn(const short* __restrict__ Q,
    const short* __restrict__ K, const short* __restrict__ Vt,
    const float* __restrict__ Tg, short* __restrict__ aout) {
  __shared__ float Tlds[3969];  // per-head 63x63 bias table (x log2e)
  const int tid = threadIdx.x, bid = blockIdx.x;
  const int h = bid & 7, qt = (bid >> 3) & 15, b = bid >> 7;
  const float* Th = Tg + (h << 12);
  for (int t = tid; t < 3969; t += 256) Tlds[t] = Th[t];
  __syncthreads();
  const int w = tid >> 6, l = tid & 63, lr = l & 15, lg = l >> 4;
  const size_t hoff = (size_t)(b * 8 + h) << 15;
  const short* Qh = Q + hoff;
  const short* Kh = K + hoff;
  const short* Vh = Vt + hoff;
  const int it = qt * 4 + w;
  const int i0 = it * 16;
  const int yi = it >> 1;
  const int pbase = ((it & 1) << 4) + lr - lg * 4 + 31;
  // Q as B-fragment: B[k=d][col=i-i0] = Q[i0+col][d]
  bf16x8 qf = *reinterpret_cast<const bf16x8*>(&Qh[(i0 + lr) * 32 + lg * 8]);
  f32x4 o0 = {0.f, 0.f, 0.f, 0.f}, o1 = {0.f, 0.f, 0.f, 0.f};
  float lsa = 0.f, lsb = 0.f;
  const float cs = 0.17677669529663688f * 1.4426950408889634f;  // scale*log2e
  // software pipeline: prefetch K/V fragments one js ahead
  const int koff0 = lr * 32 + lg * 8, koff1 = (16 + lr) * 32 + lg * 8;
  bf16x8 kf0 = *reinterpret_cast<const bf16x8*>(&Kh[koff0]);
  bf16x8 kf1 = *reinterpret_cast<const bf16x8*>(&Kh[koff1]);
  bf16x8 vf0 = *reinterpret_cast<const bf16x8*>(&Vh[koff0]);
  bf16x8 vf1 = *reinterpret_cast<const bf16x8*>(&Vh[koff1]);
  #pragma unroll 2
  for (int js = 0; js < 32; ++js) {
    const int jn = (js + 1) & 31;  // clamp: js=31 reloads js=0, unused
    bf16x8 nkf0 = *reinterpret_cast<const bf16x8*>(&Kh[(jn << 10) + koff0]);
    bf16x8 nkf1 = *reinterpret_cast<const bf16x8*>(&Kh[(jn << 10) + koff1]);
    bf16x8 nvf0 = *reinterpret_cast<const bf16x8*>(&Vh[(jn << 10) + koff0]);
    bf16x8 nvf1 = *reinterpret_cast<const bf16x8*>(&Vh[(jn << 10) + koff1]);
    f32x4 z = {0.f, 0.f, 0.f, 0.f};
    f32x4 s0 = mfma_k32(kf0, qf, z);  // S[i0+lr][j0+lg*4+r]
    f32x4 s1 = mfma_k32(kf1, qf, z);  // S[i0+lr][j0+16+lg*4+r]
    const float* Trow = &Tlds[(yi - js + 31) * 63];
    float p0[4], p1[4];
    #pragma unroll
    for (int r = 0; r < 4; ++r) {
      p0[r] = __builtin_amdgcn_exp2f(fmaf(s0[r], cs, Trow[pbase - r]));
      p1[r] = __builtin_amdgcn_exp2f(fmaf(s1[r], cs, Trow[pbase - 16 - r]));
      lsa += p0[r];
      lsb += p1[r];
    }
    // P as K=32 A-fragment under permuted k-axis (phys j = lg*4+(e&3)+16*(e>>2))
    union { int i4[4]; bf16x8 v; } pk;
    pk.i4[0] = cvt_pk_bf16(p0[0], p0[1]);
    pk.i4[1] = cvt_pk_bf16(p0[2], p0[3]);
    pk.i4[2] = cvt_pk_bf16(p1[0], p1[1]);
    pk.i4[3] = cvt_pk_bf16(p1[2], p1[3]);
    o0 = mfma_k32(pk.v, vf0, o0);  // O[i=i0+lg*4+r][d=lr]
    o1 = mfma_k32(pk.v, vf1, o1);  // O[i][d=16+lr]
    kf0 = nkf0; kf1 = nkf1; vf0 = nvf0; vf1 = nvf1;
  }
  // full row-sum for row i0+lr: reduce partials across the 4 lane-groups
  float ls = lsa + lsb;
  float s = ls + __shfl_xor(ls, 16);
  s += __shfl_xor(s, 32);
  float inv = 1.0f / s;
  #pragma unroll
  for (int r = 0; r < 4; ++r) {
    float invr = __shfl(inv, lg * 4 + r);  // sum for row i0+lg*4+r
    int n = i0 + lg * 4 + r;
    size_t base = ((size_t)b << 18) + (size_t)n * 256 + h * 32;
    aout[base + lr]      = f2bf(o0[r] * invr);
    aout[base + 16 + lr] = f2bf(o1[r] * invr);
  }
}

// ---------------- kernel 3: output projection + bias (nt split) ----------------
__global__ __launch_bounds__(256) void k_outproj(const short* __restrict__ aout,
    const short* __restrict__ WoT, const float* __restrict__ bo,
    float* __restrict__ out) {
  __shared__ short xt[64][264];
  const int tid = threadIdx.x;
  const int m0 = blockIdx.x * 64;
  const int nt0 = blockIdx.y * 8;
  for (int i = 0; i < 8; ++i) {
    int f = tid + 256 * i;
    int r = f >> 5, c8 = f & 31;
    *reinterpret_cast<bf16x8*>(&xt[r][c8 * 8]) =
        reinterpret_cast<const bf16x8*>(aout)[(size_t)(m0 + r) * 32 + c8];
  }
  __syncthreads();
  const int w = tid >> 6, l = tid & 63, lr = l & 15, lg = l >> 4;
  bf16x8 af[8];
  #pragma unroll
  for (int kc = 0; kc < 8; ++kc)
    af[kc] = *reinterpret_cast<const bf16x8*>(&xt[w * 16 + lr][kc * 32 + lg * 8]);
  #pragma unroll 4
  for (int nt = nt0; nt < nt0 + 8; ++nt) {
    f32x4 acc = {0.f, 0.f, 0.f, 0.f};
    #pragma unroll
    for (int kc = 0; kc < 8; ++kc) {
      bf16x8 bfr = *reinterpret_cast<const bf16x8*>(
          &WoT[(nt * 16 + lr) * 256 + kc * 32 + lg * 8]);
      acc = mfma_k32(af[kc], bfr, acc);
    }
    int colb = nt * 16 + lr;
    float bias = bo[colb];
    #pragma unroll
    for (int r = 0; r < 4; ++r) {
      int m = m0 + w * 16 + lg * 4 + r;
      out[(size_t)m * 256 + colb] = acc[r] + bias;
    }
  }
}

extern "C" void kernel_launch(void* const* d_in, const int* in_sizes, int n_in,
                              void* d_out, int out_size, void* d_ws, size_t ws_size,
                              hipStream_t stream) {
  const float* x  = (const float*)d_in[0];
  const float* Wq = (const float*)d_in[1];
  const float* Wk = (const float*)d_in[2];
  const float* Wv = (const float*)d_in[3];
  const float* bt = (const float*)d_in[4];
  const float* Wo = (const float*)d_in[5];
  const float* bo = (const float*)d_in[6];
  float* out = (float*)d_out;
  char* ws = (char*)d_ws;
  short* WT   = (short*)ws;                          // 4 x 65536 shorts = 512 KB
  short* Qs   = (short*)(ws + 512 * 1024);           // 8 MB each
  short* Ks   = Qs + 4194304;
  short* Vts  = Ks + 4194304;
  short* aout = Vts + 4194304;
  float* Tg   = (float*)(ws + 512 * 1024 + 4ull * 8388608);  // 8x4096 f32 = 128 KB

  k_transpose_w<<<1024, 256, 0, stream>>>(Wq, Wk, Wv, Wo, WT);
  k_bias<<<128, 256, 0, stream>>>(bt, Tg);
  k_qkv<<<dim3(256, 3), 256, 0, stream>>>(x, WT, Qs, Ks, Vts);
  k_attn<<<2048, 256, 0, stream>>>(Qs, Ks, Vts, Tg, aout);
  k_outproj<<<dim3(256, 2), 256, 0, stream>>>(aout, WT + 3 * 65536, bo, out);
}

// Round 8
// 116.860 us; speedup vs baseline: 2.0207x; 1.2400x over previous
//
#include <hip/hip_runtime.h>

// Swin-style attention: B=16, N=1024 (32x32), H=8, D=32, C=256.
// R7: k_attn processes TWO independent i-tiles per wave (rows i and i+512):
// shared K/V fragment loads, two interleaved dependency chains -> 2x ILP
// against the QK->exp->PV latency chain. Bias via compact per-head 63x63
// LDS table (R5); V in fragment-ordered subtiles (R6); transpose+bias merged.

using f32x4  = __attribute__((ext_vector_type(4))) float;
using bf16x8 = __attribute__((ext_vector_type(8))) short;

__device__ __forceinline__ short f2bf(float f) {
  union { float f; unsigned u; } v; v.f = f;
  return (short)((v.u + 0x7FFFu + ((v.u >> 16) & 1u)) >> 16);  // RNE
}
__device__ __forceinline__ f32x4 mfma_k32(bf16x8 a, bf16x8 b, f32x4 c) {
  return __builtin_amdgcn_mfma_f32_16x16x32_bf16(a, b, c, 0, 0, 0);
}
__device__ __forceinline__ int cvt_pk_bf16(float lo, float hi) {
  int r;
  asm("v_cvt_pk_bf16_f32 %0, %1, %2" : "=v"(r) : "v"(lo), "v"(hi));
  return r;
}

// ------- kernel 0: 4 weight transposes (bf16) + bias table prep, one launch ----
// blocks [0,1024): transpose; blocks [1024,1152): bias -> [h][4096] x log2e.
__global__ __launch_bounds__(256) void k_prep(const float* __restrict__ Wq,
    const float* __restrict__ Wk, const float* __restrict__ Wv,
    const float* __restrict__ Wo, short* __restrict__ WT,
    const float* __restrict__ bt, float* __restrict__ Tg) {
  int bx = blockIdx.x;
  if (bx < 1024) {
    int wid = bx >> 8, n = bx & 255, k = threadIdx.x;
    const float* W = wid == 0 ? Wq : wid == 1 ? Wk : wid == 2 ? Wv : Wo;
    WT[wid * 65536 + n * 256 + k] = f2bf(W[k * 256 + n]);
  } else {
    int idx = (bx - 1024) * 256 + threadIdx.x;  // 128 x 256 = 8 x 4096
    int h = idx >> 12, i = idx & 4095;
    if (i < 3969) Tg[idx] = bt[i * 8 + h] * 1.4426950408889634f;
  }
}

// ---------------- kernel 1: QKV projection (wi = blockIdx.y) ----------------
// V stored as fragment-ordered subtiles: Vf[((b*8+h)*32 + js)*1024 + d*32 + jp]
// where jp = lgv*8 + hi*4 + r encodes phys j = js*32 + lgv*4 + r + 16*hi.
__global__ __launch_bounds__(256) void k_qkv(const float* __restrict__ x,
    const short* __restrict__ WT,
    short* __restrict__ Q, short* __restrict__ K, short* __restrict__ Vt) {
  __shared__ short xt[64][264];
  const int tid = threadIdx.x;
  const int m0 = blockIdx.x * 64;
  const int wi = blockIdx.y;
  const short* Wt = WT + wi * 65536;
  for (int i = 0; i < 16; ++i) {
    int f = tid + 256 * i;
    int r = f >> 6, c4 = f & 63;
    float4 v = reinterpret_cast<const float4*>(x)[(size_t)(m0 + r) * 64 + c4];
    short4 s4;
    s4.x = f2bf(v.x); s4.y = f2bf(v.y); s4.z = f2bf(v.z); s4.w = f2bf(v.w);
    *reinterpret_cast<short4*>(&xt[r][c4 * 4]) = s4;
  }
  __syncthreads();
  const int w = tid >> 6, l = tid & 63, lr = l & 15, lg = l >> 4;
  bf16x8 af[8];
  #pragma unroll
  for (int kc = 0; kc < 8; ++kc)
    af[kc] = *reinterpret_cast<const bf16x8*>(&xt[w * 16 + lr][kc * 32 + lg * 8]);
  #pragma unroll 4
  for (int nt = 0; nt < 16; ++nt) {
    f32x4 acc = {0.f, 0.f, 0.f, 0.f};
    #pragma unroll
    for (int kc = 0; kc < 8; ++kc) {
      bf16x8 bfr = *reinterpret_cast<const bf16x8*>(
          &Wt[(nt * 16 + lr) * 256 + kc * 32 + lg * 8]);
      acc = mfma_k32(af[kc], bfr, acc);
    }
    int colb = nt * 16 + lr;
    int h = colb >> 5, d = colb & 31;
    if (wi == 2) {
      int m = m0 + w * 16 + lg * 4;  // 4 consecutive n (r=0..3)
      int b = m >> 10, n0 = m & 1023;
      int js = n0 >> 5;
      int lgv = (n0 & 15) >> 2, hi = (n0 >> 4) & 1;
      int jp = lgv * 8 + hi * 4;
      short4 vv;
      vv.x = f2bf(acc[0]); vv.y = f2bf(acc[1]);
      vv.z = f2bf(acc[2]); vv.w = f2bf(acc[3]);
      *reinterpret_cast<short4*>(
          &Vt[(((size_t)(b * 8 + h) * 32 + js) << 10) + d * 32 + jp]) = vv;
    } else {
      #pragma unroll
      for (int r = 0; r < 4; ++r) {
        int m = m0 + w * 16 + lg * 4 + r;
        int b = m >> 10, n = m & 1023;
        short val = f2bf(acc[r]);
        if (wi == 0)
          Q[((size_t)(b * 8 + h) * 1024 + n) * 32 + d] = val;
        else
          K[((size_t)(b * 8 + h) * 1024 + n) * 32 + d] = val;
      }
    }
  }
}

// ---------------- kernel 2: flash attention, 2 i-tiles per wave ----------------
// Block = (b, h); wave w owns i-tiles ita=qt*4+w (rows 0..511) and ita+32
// (rows 512..1023). Grid 1024 = 16b x 8qt x 8h, h in low bits (XCD locality).
__global__ __launch_bounds__(256) void k_attn(const short* __restrict__ Q,
    const short* __restrict__ K, const short* __restrict__ Vt,
    const float* __restrict__ Tg, short* __restrict__ aout) {
  __shared__ float Tlds[3969];  // per-head 63x63 bias table (x log2e)
  const int tid = threadIdx.x, bid = blockIdx.x;
  const int h = bid & 7, qt = (bid >> 3) & 7, b = bid >> 6;
  const float* Th = Tg + (h << 12);
  for (int t = tid; t < 3969; t += 256) Tlds[t] = Th[t];
  __syncthreads();
  const int w = tid >> 6, l = tid & 63, lr = l & 15, lg = l >> 4;
  const size_t hoff = (size_t)(b * 8 + h) << 15;
  const short* Qh = Q + hoff;
  const short* Kh = K + hoff;
  const short* Vh = Vt + hoff;
  const int ita = qt * 4 + w;          // 0..31
  const int i0a = ita * 16;            // rows 0..511
  const int i0b = i0a + 512;           // rows 512..1023 (same x-parity)
  const int yia = ita >> 1;
  const int pbase = ((ita & 1) << 4) + lr - lg * 4 + 31;
  bf16x8 qfa = *reinterpret_cast<const bf16x8*>(&Qh[(i0a + lr) * 32 + lg * 8]);
  bf16x8 qfb = *reinterpret_cast<const bf16x8*>(&Qh[(i0b + lr) * 32 + lg * 8]);
  f32x4 oa0 = {0.f,0.f,0.f,0.f}, oa1 = {0.f,0.f,0.f,0.f};
  f32x4 ob0 = {0.f,0.f,0.f,0.f}, ob1 = {0.f,0.f,0.f,0.f};
  float lsa = 0.f, lsb = 0.f;
  const float cs = 0.17677669529663688f * 1.4426950408889634f;  // scale*log2e
  const int koff0 = lr * 32 + lg * 8, koff1 = (16 + lr) * 32 + lg * 8;
  bf16x8 kf0 = *reinterpret_cast<const bf16x8*>(&Kh[koff0]);
  bf16x8 kf1 = *reinterpret_cast<const bf16x8*>(&Kh[koff1]);
  bf16x8 vf0 = *reinterpret_cast<const bf16x8*>(&Vh[koff0]);
  bf16x8 vf1 = *reinterpret_cast<const bf16x8*>(&Vh[koff1]);
  #pragma unroll 2
  for (int js = 0; js < 32; ++js) {
    const int jn = (js + 1) & 31;  // js=31 reloads js=0, unused
    bf16x8 nkf0 = *reinterpret_cast<const bf16x8*>(&Kh[(jn << 10) + koff0]);
    bf16x8 nkf1 = *reinterpret_cast<const bf16x8*>(&Kh[(jn << 10) + koff1]);
    bf16x8 nvf0 = *reinterpret_cast<const bf16x8*>(&Vh[(jn << 10) + koff0]);
    bf16x8 nvf1 = *reinterpret_cast<const bf16x8*>(&Vh[(jn << 10) + koff1]);
    f32x4 z = {0.f, 0.f, 0.f, 0.f};
    f32x4 sa0 = mfma_k32(kf0, qfa, z);  // S[i0a+lr][j0+lg*4+r]
    f32x4 sa1 = mfma_k32(kf1, qfa, z);  // S[i0a+lr][j0+16+lg*4+r]
    f32x4 sb0 = mfma_k32(kf0, qfb, z);  // S[i0b+lr][j0+lg*4+r]
    f32x4 sb1 = mfma_k32(kf1, qfb, z);  // S[i0b+lr][j0+16+lg*4+r]
    const float* TrowA = &Tlds[(yia - js + 31) * 63];
    const float* TrowB = TrowA + 16 * 63;  // yib = yia + 16
    float pa0[4], pa1[4], pb0[4], pb1[4];
    #pragma unroll
    for (int r = 0; r < 4; ++r) {
      pa0[r] = __builtin_amdgcn_exp2f(fmaf(sa0[r], cs, TrowA[pbase - r]));
      pa1[r] = __builtin_amdgcn_exp2f(fmaf(sa1[r], cs, TrowA[pbase - 16 - r]));
      pb0[r] = __builtin_amdgcn_exp2f(fmaf(sb0[r], cs, TrowB[pbase - r]));
      pb1[r] = __builtin_amdgcn_exp2f(fmaf(sb1[r], cs, TrowB[pbase - 16 - r]));
      lsa += pa0[r] + pa1[r];
      lsb += pb0[r] + pb1[r];
    }
    // P as K=32 A-fragment under permuted k-axis (phys j = lg*4+(e&3)+16*(e>>2))
    union { int i4[4]; bf16x8 v; } pka, pkb;
    pka.i4[0] = cvt_pk_bf16(pa0[0], pa0[1]);
    pka.i4[1] = cvt_pk_bf16(pa0[2], pa0[3]);
    pka.i4[2] = cvt_pk_bf16(pa1[0], pa1[1]);
    pka.i4[3] = cvt_pk_bf16(pa1[2], pa1[3]);
    pkb.i4[0] = cvt_pk_bf16(pb0[0], pb0[1]);
    pkb.i4[1] = cvt_pk_bf16(pb0[2], pb0[3]);
    pkb.i4[2] = cvt_pk_bf16(pb1[0], pb1[1]);
    pkb.i4[3] = cvt_pk_bf16(pb1[2], pb1[3]);
    oa0 = mfma_k32(pka.v, vf0, oa0);  // O[i0a+lg*4+r][d=lr]
    oa1 = mfma_k32(pka.v, vf1, oa1);  // O[i0a+..][d=16+lr]
    ob0 = mfma_k32(pkb.v, vf0, ob0);
    ob1 = mfma_k32(pkb.v, vf1, ob1);
    kf0 = nkf0; kf1 = nkf1; vf0 = nvf0; vf1 = nvf1;
  }
  // row-sums: reduce partials across the 4 lane-groups (row = i0+lr)
  {
    float s = lsa + __shfl_xor(lsa, 16);
    s += __shfl_xor(s, 32);
    float inv = 1.0f / s;
    #pragma unroll
    for (int r = 0; r < 4; ++r) {
      float invr = __shfl(inv, lg * 4 + r);
      int n = i0a + lg * 4 + r;
      size_t base = ((size_t)b << 18) + (size_t)n * 256 + h * 32;
      aout[base + lr]      = f2bf(oa0[r] * invr);
      aout[base + 16 + lr] = f2bf(oa1[r] * invr);
    }
  }
  {
    float s = lsb + __shfl_xor(lsb, 16);
    s += __shfl_xor(s, 32);
    float inv = 1.0f / s;
    #pragma unroll
    for (int r = 0; r < 4; ++r) {
      float invr = __shfl(inv, lg * 4 + r);
      int n = i0b + lg * 4 + r;
      size_t base = ((size_t)b << 18) + (size_t)n * 256 + h * 32;
      aout[base + lr]      = f2bf(ob0[r] * invr);
      aout[base + 16 + lr] = f2bf(ob1[r] * invr);
    }
  }
}

// ---------------- kernel 3: output projection + bias (nt split) ----------------
__global__ __launch_bounds__(256) void k_outproj(const short* __restrict__ aout,
    const short* __restrict__ WoT, const float* __restrict__ bo,
    float* __restrict__ out) {
  __shared__ short xt[64][264];
  const int tid = threadIdx.x;
  const int m0 = blockIdx.x * 64;
  const int nt0 = blockIdx.y * 8;
  for (int i = 0; i < 8; ++i) {
    int f = tid + 256 * i;
    int r = f >> 5, c8 = f & 31;
    *reinterpret_cast<bf16x8*>(&xt[r][c8 * 8]) =
        reinterpret_cast<const bf16x8*>(aout)[(size_t)(m0 + r) * 32 + c8];
  }
  __syncthreads();
  const int w = tid >> 6, l = tid & 63, lr = l & 15, lg = l >> 4;
  bf16x8 af[8];
  #pragma unroll
  for (int kc = 0; kc < 8; ++kc)
    af[kc] = *reinterpret_cast<const bf16x8*>(&xt[w * 16 + lr][kc * 32 + lg * 8]);
  #pragma unroll 4
  for (int nt = nt0; nt < nt0 + 8; ++nt) {
    f32x4 acc = {0.f, 0.f, 0.f, 0.f};
    #pragma unroll
    for (int kc = 0; kc < 8; ++kc) {
      bf16x8 bfr = *reinterpret_cast<const bf16x8*>(
          &WoT[(nt * 16 + lr) * 256 + kc * 32 + lg * 8]);
      acc = mfma_k32(af[kc], bfr, acc);
    }
    int colb = nt * 16 + lr;
    float bias = bo[colb];
    #pragma unroll
    for (int r = 0; r < 4; ++r) {
      int m = m0 + w * 16 + lg * 4 + r;
      out[(size_t)m * 256 + colb] = acc[r] + bias;
    }
  }
}

extern "C" void kernel_launch(void* const* d_in, const int* in_sizes, int n_in,
                              void* d_out, int out_size, void* d_ws, size_t ws_size,
                              hipStream_t stream) {
  const float* x  = (const float*)d_in[0];
  const float* Wq = (const float*)d_in[1];
  const float* Wk = (const float*)d_in[2];
  const float* Wv = (const float*)d_in[3];
  const float* bt = (const float*)d_in[4];
  const float* Wo = (const float*)d_in[5];
  const float* bo = (const float*)d_in[6];
  float* out = (float*)d_out;
  char* ws = (char*)d_ws;
  short* WT   = (short*)ws;                          // 4 x 65536 shorts = 512 KB
  short* Qs   = (short*)(ws + 512 * 1024);           // 8 MB each
  short* Ks   = Qs + 4194304;
  short* Vts  = Ks + 4194304;
  short* aout = Vts + 4194304;
  float* Tg   = (float*)(ws + 512 * 1024 + 4ull * 8388608);  // 8x4096 f32 = 128 KB

  k_prep<<<1152, 256, 0, stream>>>(Wq, Wk, Wv, Wo, WT, bt, Tg);
  k_qkv<<<dim3(256, 3), 256, 0, stream>>>(x, WT, Qs, Ks, Vts);
  k_attn<<<1024, 256, 0, stream>>>(Qs, Ks, Vts, Tg, aout);
  k_outproj<<<dim3(256, 2), 256, 0, stream>>>(aout, WT + 3 * 65536, bo, out);
}